// Round 1
// baseline (366.022 us; speedup 1.0000x reference)
//
#include <hip/hip_runtime.h>
#include <math.h>

// SFNAttention on MI355X (gfx950).
// Pipeline:
//   P0: split x -> A' = [xh | xl | xh]            bf16 [4096, 3072]
//   P1: split Wq/Wk/Wv -> Wc = rows [3*1024] x [wh | wh | wl]  bf16 [3072, 3072]
//   P2: cast Wo -> bf16 [1024, 1024]
//   G1: C = A' @ Wc^T  (split-bf16 == fp32-accurate x@W.T), epilogue:
//       +bias, sfn, (q,k): RMS-norm over head dim (wave-local shuffle reduce),
//       store q,k bf16 [B,H,L,Dh]; v: store bf16 transposed [B,H,Dh,L]
//   A : flash attention, swapped QK^T (S^T = mfma(K, Q)), online softmax,
//       in-register P^T redistribution via shfl, PV with V^T A-frags.
//       store attn bf16 [4096, 1024]
//   G2: out = attn @ Wo^T + bo, fp32 [4096, 1024]

typedef __bf16 bf16;
typedef bf16 bf16x4 __attribute__((ext_vector_type(4)));
typedef bf16 bf16x8 __attribute__((ext_vector_type(8)));
typedef float f32x4 __attribute__((ext_vector_type(4)));

#define LOG2E 1.4426950408889634f

__device__ __forceinline__ float sfn_f(float x) {
  // clip(rint(x/0.5), -8, 8) * 0.5 ; rintf = round-half-even, matches jnp.round
  return fminf(fmaxf(rintf(x + x), -8.0f), 8.0f) * 0.5f;
}

// ---------------- prep kernels ----------------

__global__ __launch_bounds__(256) void prep_x_kernel(const float* __restrict__ x,
                                                     bf16* __restrict__ ax) {
  int idx = blockIdx.x * 256 + threadIdx.x;   // 1,048,576 = 4096*1024/4
  int m  = idx >> 8;
  int kc = (idx & 255) << 2;
  const float4 v = *(const float4*)(x + (size_t)m * 1024 + kc);
  bf16 h0 = (bf16)v.x, h1 = (bf16)v.y, h2 = (bf16)v.z, h3 = (bf16)v.w;
  bf16 l0 = (bf16)(v.x - (float)h0), l1 = (bf16)(v.y - (float)h1),
       l2 = (bf16)(v.z - (float)h2), l3 = (bf16)(v.w - (float)h3);
  bf16x4 hv = {h0, h1, h2, h3};
  bf16x4 lv = {l0, l1, l2, l3};
  bf16* p = ax + (size_t)m * 3072 + kc;
  *(bf16x4*)(p)        = hv;
  *(bf16x4*)(p + 1024) = lv;
  *(bf16x4*)(p + 2048) = hv;
}

__global__ __launch_bounds__(256) void prep_w_kernel(const float* __restrict__ Wq,
                                                     const float* __restrict__ Wk,
                                                     const float* __restrict__ Wv,
                                                     bf16* __restrict__ wc) {
  int idx = blockIdx.x * 256 + threadIdx.x;   // 786,432 = 3*1024*1024/4
  int mat = idx >> 18;
  int r   = idx & 262143;
  int n   = r >> 8;
  int kc  = (r & 255) << 2;
  const float* W = (mat == 0) ? Wq : ((mat == 1) ? Wk : Wv);
  const float4 v = *(const float4*)(W + (size_t)n * 1024 + kc);
  bf16 h0 = (bf16)v.x, h1 = (bf16)v.y, h2 = (bf16)v.z, h3 = (bf16)v.w;
  bf16 l0 = (bf16)(v.x - (float)h0), l1 = (bf16)(v.y - (float)h1),
       l2 = (bf16)(v.z - (float)h2), l3 = (bf16)(v.w - (float)h3);
  bf16x4 hv = {h0, h1, h2, h3};
  bf16x4 lv = {l0, l1, l2, l3};
  bf16* p = wc + (size_t)(mat * 1024 + n) * 3072 + kc;
  *(bf16x4*)(p)        = hv;
  *(bf16x4*)(p + 1024) = hv;
  *(bf16x4*)(p + 2048) = lv;
}

__global__ __launch_bounds__(256) void prep_wo_kernel(const float* __restrict__ Wo,
                                                      bf16* __restrict__ wob) {
  int idx = blockIdx.x * 256 + threadIdx.x;   // 262,144 = 1024*1024/4
  const float4 v = *(const float4*)(Wo + (size_t)idx * 4);
  bf16x4 hv = {(bf16)v.x, (bf16)v.y, (bf16)v.z, (bf16)v.w};
  *(bf16x4*)(wob + (size_t)idx * 4) = hv;
}

// ---------------- GEMM (C[m,n] = sum_k A[m,k] * B[n,k]) ----------------
// 128x128 tile, BK=32, 4 waves each computing a 64x64 subtile of 4x4 16x16x32
// MFMA fragments.  MODE 0: QKV epilogue (bias+sfn+qknorm / v-transpose store).
// MODE 1: final projection epilogue (+bo, fp32 store).

template <int MODE>
__global__ __launch_bounds__(256) void gemm_bt_kernel(
    const bf16* __restrict__ A, const bf16* __restrict__ Bm, int K,
    const float* __restrict__ b0, const float* __restrict__ b1,
    const float* __restrict__ b2, const float* __restrict__ g0,
    const float* __restrict__ g1, bf16* __restrict__ qn, bf16* __restrict__ kn,
    bf16* __restrict__ vt, float* __restrict__ outf) {
  __shared__ bf16 sA[128 * 32];
  __shared__ bf16 sB[128 * 32];
  const int tid  = threadIdx.x;
  const int wave = tid >> 6;
  const int lane = tid & 63;
  const int lm   = lane & 15;
  const int kg   = lane >> 4;
  const int m0 = blockIdx.y << 7;
  const int n0 = blockIdx.x << 7;
  const int wm = (wave >> 1) << 6;
  const int wn = (wave & 1) << 6;

  const int rA0 = tid >> 2;
  const int kc0 = (tid & 3) << 3;
  const int rA1 = rA0 + 64;

  f32x4 acc[4][4] = {};

  for (int kt = 0; kt < K; kt += 32) {
    __syncthreads();
    *(uint4*)(sA + rA0 * 32 + kc0) = *(const uint4*)(A  + (size_t)(m0 + rA0) * K + kt + kc0);
    *(uint4*)(sA + rA1 * 32 + kc0) = *(const uint4*)(A  + (size_t)(m0 + rA1) * K + kt + kc0);
    *(uint4*)(sB + rA0 * 32 + kc0) = *(const uint4*)(Bm + (size_t)(n0 + rA0) * K + kt + kc0);
    *(uint4*)(sB + rA1 * 32 + kc0) = *(const uint4*)(Bm + (size_t)(n0 + rA1) * K + kt + kc0);
    __syncthreads();
    bf16x8 af[4], bfv[4];
#pragma unroll
    for (int r = 0; r < 4; ++r)
      af[r] = *(const bf16x8*)(sA + (wm + 16 * r + lm) * 32 + kg * 8);
#pragma unroll
    for (int c = 0; c < 4; ++c)
      bfv[c] = *(const bf16x8*)(sB + (wn + 16 * c + lm) * 32 + kg * 8);
#pragma unroll
    for (int r = 0; r < 4; ++r)
#pragma unroll
      for (int c = 0; c < 4; ++c)
        acc[r][c] = __builtin_amdgcn_mfma_f32_16x16x32_bf16(af[r], bfv[c], acc[r][c], 0, 0, 0);
  }

  if (MODE == 0) {
    const int ncb = n0 + wn;        // 64-aligned: one head per wave subtile
    const int mat = ncb >> 10;      // 0=q 1=k 2=v
    const int nin = ncb & 1023;
    const int hh  = nin >> 6;
    const float* bias = (mat == 0) ? b0 : ((mat == 1) ? b1 : b2);
    float bvals[4];
#pragma unroll
    for (int c = 0; c < 4; ++c) bvals[c] = bias[nin + 16 * c + lm];

    if (mat < 2) {
      const float* gain = (mat == 0) ? g0 : g1;
      bf16* dst = (mat == 0) ? qn : kn;
      float gv[4];
#pragma unroll
      for (int c = 0; c < 4; ++c) gv[c] = gain[16 * c + lm];
#pragma unroll
      for (int r = 0; r < 4; ++r) {
        float y[4][4];              // [c][reg]
        float ss[4] = {0.f, 0.f, 0.f, 0.f};
#pragma unroll
        for (int c = 0; c < 4; ++c)
#pragma unroll
          for (int g = 0; g < 4; ++g) {
            float t = sfn_f(acc[r][c][g] + bvals[c]);
            y[c][g] = t;
            ss[g] += t * t;
          }
#pragma unroll
        for (int g = 0; g < 4; ++g) {   // reduce over the 16-lane (lm) group
          float s = ss[g];
          s += __shfl_xor(s, 1);
          s += __shfl_xor(s, 2);
          s += __shfl_xor(s, 4);
          s += __shfl_xor(s, 8);
          ss[g] = 1.0f / sqrtf(s * (1.0f / 64.0f) + 1e-6f);
        }
        const int mbase = m0 + wm + 16 * r + 4 * kg;
        const int bb = mbase >> 11;
        const int ll = mbase & 2047;
#pragma unroll
        for (int g = 0; g < 4; ++g) {
          bf16* rowp = dst + ((size_t)(bb * 16 + hh) * 2048 + (ll + g)) * 64;
#pragma unroll
          for (int c = 0; c < 4; ++c)
            rowp[16 * c + lm] = (bf16)(y[c][g] * ss[g] * gv[c]);
        }
      }
    } else {
      // v: sfn only, store transposed [B,H,Dh,L]
#pragma unroll
      for (int r = 0; r < 4; ++r) {
        const int mbase = m0 + wm + 16 * r + 4 * kg;
        const int bb = mbase >> 11;
        const int ll = mbase & 2047;
#pragma unroll
        for (int c = 0; c < 4; ++c) {
          bf16x4 pk;
#pragma unroll
          for (int g = 0; g < 4; ++g)
            pk[g] = (bf16)sfn_f(acc[r][c][g] + bvals[c]);
          *(bf16x4*)(vt + ((size_t)(bb * 16 + hh) * 64 + 16 * c + lm) * 2048 + ll) = pk;
        }
      }
    }
  } else {
    float bvals[4];
#pragma unroll
    for (int c = 0; c < 4; ++c) bvals[c] = b0[n0 + wn + 16 * c + lm];
#pragma unroll
    for (int r = 0; r < 4; ++r) {
      const int mr = m0 + wm + 16 * r + 4 * kg;
#pragma unroll
      for (int c = 0; c < 4; ++c) {
        const int nc = n0 + wn + 16 * c + lm;
#pragma unroll
        for (int g = 0; g < 4; ++g)
          outf[(size_t)(mr + g) * 1024 + nc] = acc[r][c][g] + bvals[c];
      }
    }
  }
}

// ---------------- attention ----------------
// grid (L/128, B*H), 256 thr = 4 waves, each wave owns 32 q rows.
// S^T = mfma(K, Q): C-frag row = k (16rb + 4*kg + reg), col = q (16c + lm).
// Softmax state per (c, lm); reduce across the 4 kg groups via shfl xor 16,32.
// P^T redistributed to B-frags in-register (2-pass shfl), PV uses V^T A-frags.

__global__ __launch_bounds__(256) void attn_kernel(const bf16* __restrict__ qn,
                                                   const bf16* __restrict__ kn,
                                                   const bf16* __restrict__ vt,
                                                   bf16* __restrict__ ao) {
  const int tid  = threadIdx.x;
  const int wave = tid >> 6;
  const int lane = tid & 63;
  const int lm   = lane & 15;
  const int kg   = lane >> 4;
  const int bh   = blockIdx.y;
  const int q0   = (blockIdx.x << 7) + (wave << 5);
  const bf16* qb = qn + (size_t)bh * 2048 * 64;
  const bf16* kb = kn + (size_t)bh * 2048 * 64;
  const bf16* vb = vt + (size_t)bh * 64 * 2048;

  bf16x8 qf[2][2];
#pragma unroll
  for (int c = 0; c < 2; ++c)
#pragma unroll
    for (int dh = 0; dh < 2; ++dh)
      qf[c][dh] = *(const bf16x8*)(qb + (size_t)(q0 + 16 * c + lm) * 64 + dh * 32 + kg * 8);

  f32x4 o[4][2] = {};
  float mrun[2] = {-INFINITY, -INFINITY};
  float lrun[2] = {0.f, 0.f};

  for (int kt = 0; kt < 2048; kt += 64) {
    bf16x8 ka[4][2];
#pragma unroll
    for (int rb = 0; rb < 4; ++rb)
#pragma unroll
      for (int dh = 0; dh < 2; ++dh)
        ka[rb][dh] = *(const bf16x8*)(kb + (size_t)(kt + 16 * rb + lm) * 64 + dh * 32 + kg * 8);

    f32x4 s[4][2] = {};
#pragma unroll
    for (int rb = 0; rb < 4; ++rb)
#pragma unroll
      for (int c = 0; c < 2; ++c)
#pragma unroll
        for (int dh = 0; dh < 2; ++dh)
          s[rb][c] = __builtin_amdgcn_mfma_f32_16x16x32_bf16(ka[rb][dh], qf[c][dh], s[rb][c], 0, 0, 0);

#pragma unroll
    for (int rb = 0; rb < 4; ++rb)
#pragma unroll
      for (int c = 0; c < 2; ++c)
#pragma unroll
        for (int g = 0; g < 4; ++g)
          s[rb][c][g] *= 0.125f;   // Dh^-0.5

#pragma unroll
    for (int c = 0; c < 2; ++c) {
      float mx = -INFINITY;
#pragma unroll
      for (int rb = 0; rb < 4; ++rb)
#pragma unroll
        for (int g = 0; g < 4; ++g)
          mx = fmaxf(mx, s[rb][c][g]);
      mx = fmaxf(mx, __shfl_xor(mx, 16));
      mx = fmaxf(mx, __shfl_xor(mx, 32));
      const float mnew = fmaxf(mrun[c], mx);
      const float corr = exp2f((mrun[c] - mnew) * LOG2E);
      mrun[c] = mnew;
      float psum = 0.f;
#pragma unroll
      for (int rb = 0; rb < 4; ++rb)
#pragma unroll
        for (int g = 0; g < 4; ++g) {
          float p = exp2f((s[rb][c][g] - mnew) * LOG2E);
          s[rb][c][g] = p;
          psum += p;
        }
      psum += __shfl_xor(psum, 16);
      psum += __shfl_xor(psum, 32);
      lrun[c] = lrun[c] * corr + psum;
#pragma unroll
      for (int rbd = 0; rbd < 4; ++rbd)
#pragma unroll
        for (int g = 0; g < 4; ++g)
          o[rbd][c][g] *= corr;
    }

    // P^T[k][q] -> B-frags: lane (kg,lm) needs k = 32*kh + 8*kg + j at q=16c+lm.
    // source: rb = 2*kh + (kg>>1), group g' = 2*(kg&1) + (j>>2), reg = j&3.
    bf16x8 pb[2][2];
#pragma unroll
    for (int c = 0; c < 2; ++c)
#pragma unroll
      for (int kh = 0; kh < 2; ++kh)
#pragma unroll
        for (int j = 0; j < 8; ++j) {
          const int src = lm + 16 * (2 * (kg & 1) + (j >> 2));
          float v0 = __shfl(s[2 * kh + 0][c][j & 3], src);
          float v1 = __shfl(s[2 * kh + 1][c][j & 3], src);
          pb[c][kh][j] = (bf16)((kg & 2) ? v1 : v0);
        }

    bf16x8 va[4][2];
#pragma unroll
    for (int rbd = 0; rbd < 4; ++rbd)
#pragma unroll
      for (int kh = 0; kh < 2; ++kh)
        va[rbd][kh] = *(const bf16x8*)(vb + (size_t)(16 * rbd + lm) * 2048 + kt + kh * 32 + kg * 8);

#pragma unroll
    for (int rbd = 0; rbd < 4; ++rbd)
#pragma unroll
      for (int c = 0; c < 2; ++c)
#pragma unroll
        for (int kh = 0; kh < 2; ++kh)
          o[rbd][c] = __builtin_amdgcn_mfma_f32_16x16x32_bf16(va[rbd][kh], pb[c][kh], o[rbd][c], 0, 0, 0);
  }

  const int bb = bh >> 4;
  const int hh = bh & 15;
#pragma unroll
  for (int c = 0; c < 2; ++c) {
    const float inv = 1.0f / lrun[c];
    const int q = q0 + 16 * c + lm;
    bf16* rowp = ao + (size_t)(bb * 2048 + q) * 1024 + hh * 64;
#pragma unroll
    for (int rbd = 0; rbd < 4; ++rbd) {
      bf16x4 pk;
#pragma unroll
      for (int g = 0; g < 4; ++g)
        pk[g] = (bf16)(o[rbd][c][g] * inv);
      *(bf16x4*)(rowp + 16 * rbd + 4 * kg) = pk;
    }
  }
}

// ---------------- launch ----------------

extern "C" void kernel_launch(void* const* d_in, const int* in_sizes, int n_in,
                              void* d_out, int out_size, void* d_ws, size_t ws_size,
                              hipStream_t stream) {
  const float* x  = (const float*)d_in[0];
  const float* Wq = (const float*)d_in[1];
  const float* bq = (const float*)d_in[2];
  const float* Wk = (const float*)d_in[3];
  const float* bk = (const float*)d_in[4];
  const float* Wv = (const float*)d_in[5];
  const float* bv = (const float*)d_in[6];
  const float* Wo = (const float*)d_in[7];
  const float* bo = (const float*)d_in[8];
  const float* gq = (const float*)d_in[9];
  const float* gk = (const float*)d_in[10];
  float* out = (float*)d_out;

  char* ws = (char*)d_ws;
  // ws layout (total 79,691,776 B)
  bf16* ax   = (bf16*)(ws);                    // [4096,3072]  25,165,824
  bf16* wc   = (bf16*)(ws + 25165824);         // [3072,3072]  18,874,368
  bf16* wob  = (bf16*)(ws + 44040192);         // [1024,1024]   2,097,152
  bf16* qn   = (bf16*)(ws + 46137344);         // [B,H,L,Dh]    8,388,608
  bf16* kn   = (bf16*)(ws + 54525952);         // [B,H,L,Dh]    8,388,608
  bf16* vt   = (bf16*)(ws + 62914560);         // [B,H,Dh,L]    8,388,608
  bf16* attn = (bf16*)(ws + 71303168);         // [4096,1024]   8,388,608

  prep_x_kernel<<<dim3(4096), dim3(256), 0, stream>>>(x, ax);
  prep_w_kernel<<<dim3(3072), dim3(256), 0, stream>>>(Wq, Wk, Wv, wc);
  prep_wo_kernel<<<dim3(1024), dim3(256), 0, stream>>>(Wo, wob);

  gemm_bt_kernel<0><<<dim3(24, 32), dim3(256), 0, stream>>>(
      ax, wc, 3072, bq, bk, bv, gq, gk, qn, kn, vt, nullptr);

  attn_kernel<<<dim3(16, 32), dim3(256), 0, stream>>>(qn, kn, vt, attn);

  gemm_bt_kernel<1><<<dim3(8, 32), dim3(256), 0, stream>>>(
      attn, wob, 1024, bo, nullptr, nullptr, nullptr, nullptr,
      nullptr, nullptr, nullptr, out);
}